// Round 6
// baseline (604.932 us; speedup 1.0000x reference)
//
#include <hip/hip_runtime.h>

#define B 64
#define P 16320
#define NOBJ 32
#define NC 21
#define TPB 512
#define NCH 32   // ceil(P/TPB); last chunk has 128 valid priors

__device__ constexpr float LN99 = 4.59511985013459f;  // softmax(c1)>0.01 <=> c0-c1 < ln99
#define SENT 0x407FFFFFFFFFFFFFULL                     // pack(-1.0f, prior 0)

struct Box { float x1, y1, x2, y2, area; };

__device__ __forceinline__ Box decode_box(float4 l, float4 pr) {
    Box b;
    float dcx = pr.x + l.x * 0.1f * pr.z;
    float dcy = pr.y + l.y * 0.1f * pr.w;
    float dw = pr.z * __expf(l.z * 0.2f);
    float dh = pr.w * __expf(l.w * 0.2f);
    b.x1 = dcx - dw * 0.5f; b.y1 = dcy - dh * 0.5f;
    b.x2 = dcx + dw * 0.5f; b.y2 = dcy + dh * 0.5f;
    b.area = (b.x2 - b.x1) * (b.y2 - b.y1);
    return b;
}
__device__ __forceinline__ float iou_box(const Box& bb, float4 t, float ta) {
    float iw = fmaxf(fminf(bb.x2, t.z) - fmaxf(bb.x1, t.x), 0.f);
    float ih = fmaxf(fminf(bb.y2, t.w) - fmaxf(bb.y1, t.y), 0.f);
    float inter = iw * ih;
    return inter * __builtin_amdgcn_rcpf(ta + bb.area - inter);
}
__device__ __forceinline__ float smoothl1(const Box& bb, float4 tb, float4 ol) {
    float rcx = (bb.x1 + bb.x2) * 0.5f, rcy = (bb.y1 + bb.y2) * 0.5f;
    float rw = bb.x2 - bb.x1, rh = bb.y2 - bb.y1;
    float g0 = ((tb.x + tb.z) * 0.5f - rcx) * __builtin_amdgcn_rcpf(0.1f * rw);
    float g1 = ((tb.y + tb.w) * 0.5f - rcy) * __builtin_amdgcn_rcpf(0.1f * rh);
    float g2 = __logf((tb.z - tb.x) * __builtin_amdgcn_rcpf(rw)) * 5.0f;
    float g3 = __logf((tb.w - tb.y) * __builtin_amdgcn_rcpf(rh)) * 5.0f;
    float gt[4] = {g0, g1, g2, g3};
    float od[4] = {ol.x, ol.y, ol.z, ol.w};
    float s = 0.f;
    #pragma unroll
    for (int k = 0; k < 4; k++) {
        float d = fabsf(od[k] - gt[k]);
        s += (d < 1.f) ? 0.5f * d * d : d - 0.5f;
    }
    return s;
}
__device__ __forceinline__ float lse_row(const float* row) {
    float m = row[0];
    #pragma unroll
    for (int k = 1; k < NC; k++) m = fmaxf(m, row[k]);
    float s = 0.f;
    #pragma unroll
    for (int k = 0; k < NC; k++) s += __expf(row[k] - m);
    return m + __logf(s);
}

// ---------------- k_main: decode + IoU + argmaxes + CE + losses + mine -------
// Grid (NCH, B), TPB threads = TPB priors. Per-truth winners via value-filtered
// LDS u64 atomicMax; per-block partial sums (no global atomics, no init kernel).
__global__ __launch_bounds__(TPB) void k_main(
    const float* __restrict__ arm_loc, const float* __restrict__ arm_conf,
    const float* __restrict__ odm_loc, const float* __restrict__ odm_conf,
    const float* __restrict__ priors, const float* __restrict__ truths,
    const int* __restrict__ labels,
    float* __restrict__ mine, unsigned long long* __restrict__ bp_part,
    float* __restrict__ pll, float* __restrict__ plc, int* __restrict__ pnp)
{
    int b = blockIdx.y, ch = blockIdx.x;
    int tid = threadIdx.x;
    int pbase = ch * TPB;
    int p = pbase + tid;
    bool active = p < P;

    __shared__ float soc[TPB * NC];      // 43008 B
    __shared__ float4 s_tr[NOBJ];
    __shared__ float s_ta[NOBJ];
    __shared__ int s_lab[NOBJ];
    __shared__ unsigned long long s_bp[NOBJ];
    __shared__ float sll[TPB / 64], slc[TPB / 64];
    __shared__ int snp[TPB / 64];

    if (tid < NOBJ) {
        float4 t = ((const float4*)truths)[b * NOBJ + tid];
        s_tr[tid] = t;
        s_ta[tid] = (t.z - t.x) * (t.w - t.y);
        s_lab[tid] = labels[b * NOBJ + tid];
        s_bp[tid] = 0ULL;
    }
    {   // coalesced float4 staging of odm_conf
        int nval = P - pbase; if (nval > TPB) nval = TPB;
        int tot4 = (nval * NC) >> 2;                  // divisible (512*21, 128*21)
        const float4* src = (const float4*)(odm_conf + ((size_t)b * P + pbase) * NC);
        float4* dst = (float4*)soc;
        for (int i = tid; i < tot4; i += TPB) dst[i] = src[i];
    }
    __syncthreads();

    Box bb = {0.f, 0.f, 0.f, 0.f, 0.f};
    bool resv = false;
    if (active) {
        size_t bpi = (size_t)b * P + p;
        float2 cc = ((const float2*)arm_conf)[bpi];
        resv = (cc.x - cc.y) < LN99;
        bb = decode_box(((const float4*)arm_loc)[bpi], ((const float4*)priors)[p]);
    }

    float bv = -1.f; int bj = 0;
    volatile unsigned* bp_hi = (volatile unsigned*)s_bp;
    #pragma unroll
    for (int j = 0; j < NOBJ; j++) {
        float iou = iou_box(bb, s_tr[j], s_ta[j]);
        if (iou > bv) { bv = iou; bj = j; }           // first-max tie-break
        if (resv) {
            unsigned hv = __float_as_uint(iou) | 0x80000000u;   // iou>=0 monotone
            if (hv >= bp_hi[2 * j + 1]) {             // value filter (>= keeps p-ties)
                unsigned long long key =
                    ((unsigned long long)hv << 32) | (unsigned)~(unsigned)p;
                atomicMax(&s_bp[j], key);
            }
        }
    }

    int conf = -1;
    if (active) conf = resv ? ((bv >= 0.5f) ? s_lab[bj] + 1 : 0) : -1;

    float ll = 0.f, lc = 0.f; int np = 0;
    if (active) {
        size_t bpi = (size_t)b * P + p;
        const float* row = &soc[tid * NC];
        float lse = lse_row(row);
        int t0 = conf > 0 ? conf : 0;
        float ce = lse - row[t0];
        mine[bpi] = (conf == 0) ? ce : 0.f;
        if (conf > 0) {
            np = 1; lc = ce;
            float4 ol = ((const float4*)odm_loc)[bpi];
            ll = smoothl1(bb, s_tr[bj], ol);
        }
    }

    #pragma unroll
    for (int off = 32; off; off >>= 1) {
        ll += __shfl_xor(ll, off, 64);
        lc += __shfl_xor(lc, off, 64);
        np += __shfl_xor(np, off, 64);
    }
    int wid = tid >> 6, lane = tid & 63;
    if (lane == 0) { sll[wid] = ll; slc[wid] = lc; snp[wid] = np; }
    __syncthreads();   // also guarantees all s_bp atomics landed

    if (tid < NOBJ) bp_part[((size_t)b * NCH + ch) * NOBJ + tid] = s_bp[tid];
    if (tid == 0) {
        float a = 0.f, c = 0.f; int n = 0;
        #pragma unroll
        for (int w = 0; w < TPB / 64; w++) { a += sll[w]; c += slc[w]; n += snp[w]; }
        int idx = b * NCH + ch;
        pll[idx] = a; plc[idx] = c; pnp[idx] = n;
    }
}

// ---------------- k_fix: combine partials + apply force-match deltas ---------
// One single-wave block per batch. Lanes 0..31: chunk partial sums AND per-truth
// winner handling (dedup: largest j wins = JAX last-write). Writes final sums.
__global__ __launch_bounds__(64) void k_fix(
    const float* __restrict__ arm_loc, const float* __restrict__ arm_conf,
    const float* __restrict__ odm_loc, const float* __restrict__ odm_conf,
    const float* __restrict__ priors, const float* __restrict__ truths,
    const int* __restrict__ labels,
    const unsigned long long* __restrict__ bp_part,
    const float* __restrict__ pll, const float* __restrict__ plc,
    const int* __restrict__ pnp,
    float* __restrict__ mine, float* __restrict__ ll_b, float* __restrict__ lc_b,
    int* __restrict__ num_pos)
{
    int b = blockIdx.x;
    int tid = threadIdx.x;   // one wave

    __shared__ float4 s_tr[NOBJ];
    __shared__ float s_ta[NOBJ];
    __shared__ int s_lab[NOBJ];
    __shared__ unsigned s_p[NOBJ];

    if (tid < NOBJ) {
        float4 t = ((const float4*)truths)[b * NOBJ + tid];
        s_tr[tid] = t;
        s_ta[tid] = (t.z - t.x) * (t.w - t.y);
        s_lab[tid] = labels[b * NOBJ + tid];
    }

    float ll = 0.f, lc = 0.f; int np = 0;
    if (tid < NCH) {
        int idx = b * NCH + tid;
        ll = pll[idx]; lc = plc[idx]; np = pnp[idx];
    }

    if (tid < NOBJ) {
        unsigned long long m = SENT;
        for (int c = 0; c < NCH; c++) {
            unsigned long long v = bp_part[((size_t)b * NCH + c) * NOBJ + tid];
            if (v > m) m = v;
        }
        s_p[tid] = ~(unsigned)(m & 0xFFFFFFFFULL);
    }

    if (tid < NOBJ) {
        unsigned pstar = s_p[tid];
        bool alive = true;
        for (int j2 = tid + 1; j2 < NOBJ; j2++)
            if (s_p[j2] == pstar) alive = false;      // last j wins (JAX scatter)
        if (alive) {
            size_t bpi = (size_t)b * P + pstar;
            float2 cc = ((const float2*)arm_conf)[bpi];
            bool resv = (cc.x - cc.y) < LN99;
            if (resv) {   // non-reserve forced prior stays conf=-1 (ref order)
                Box bb = decode_box(((const float4*)arm_loc)[bpi],
                                    ((const float4*)priors)[pstar]);
                float bv = -1.f; int bj = 0;
                #pragma unroll
                for (int j = 0; j < NOBJ; j++) {
                    float iou = iou_box(bb, s_tr[j], s_ta[j]);
                    if (iou > bv) { bv = iou; bj = j; }
                }
                int old_conf = (bv >= 0.5f) ? s_lab[bj] + 1 : 0;
                const float* row = odm_conf + bpi * NC;
                float lse = lse_row(row);
                int new_conf = s_lab[tid] + 1;
                float ce_new = lse - row[new_conf];
                float4 ol = ((const float4*)odm_loc)[bpi];
                float sl_new = smoothl1(bb, s_tr[tid], ol);
                if (old_conf > 0) {
                    float ce_old = lse - row[old_conf];
                    float sl_old = smoothl1(bb, s_tr[bj], ol);
                    lc += ce_new - ce_old;
                    ll += sl_new - sl_old;
                    // np unchanged; mine[pstar] already 0 (was positive)
                } else {
                    lc += ce_new; ll += sl_new; np += 1;
                    mine[bpi] = 0.f;                  // was a mining candidate
                }
            }
        }
    }

    #pragma unroll
    for (int off = 32; off; off >>= 1) {
        ll += __shfl_xor(ll, off, 64);
        lc += __shfl_xor(lc, off, 64);
        np += __shfl_xor(np, off, 64);
    }
    if (tid == 0) { ll_b[b] = ll; lc_b[b] = lc; num_pos[b] = np; }
}

// ---------------- per-batch top-K CE sum: LDS-resident radix select ----------
__global__ __launch_bounds__(1024) void k_select(
    const float* __restrict__ mine, const int* __restrict__ num_pos,
    float* __restrict__ lc_b)
{
    int b = blockIdx.x, tid = threadIdx.x;
    int K0 = num_pos[b] * 3;
    if (K0 > P - 1) K0 = P - 1;
    if (K0 <= 0) return;

    __shared__ float4 s_row4[P / 4];        // 65280 B
    __shared__ unsigned hist[16 * 257];     // per-wave + pad
    __shared__ unsigned s_merged[256];
    __shared__ unsigned s_beta, s_K;
    __shared__ float sS[16];
    __shared__ unsigned sM[16];

    const float4* src = (const float4*)(mine + (size_t)b * P);
    for (int i = tid; i < P / 4; i += 1024) s_row4[i] = src[i];

    unsigned K = (unsigned)K0, prefix = 0, maskDone = 0;
    int wid = tid >> 6;

    for (int pass = 0; pass < 4; pass++) {
        int shift = 24 - pass * 8;
        for (int i = tid; i < 16 * 257; i += 1024) hist[i] = 0;
        __syncthreads();
        for (int i = tid; i < P / 4; i += 1024) {
            float4 v = s_row4[i];
            float vv[4] = {v.x, v.y, v.z, v.w};
            #pragma unroll
            for (int e = 0; e < 4; e++) {
                unsigned bits = __float_as_uint(vv[e]);
                if ((bits & maskDone) == prefix)
                    atomicAdd(&hist[wid * 257 + ((bits >> shift) & 255u)], 1u);
            }
        }
        __syncthreads();
        if (tid < 256) {
            unsigned t = 0;
            #pragma unroll
            for (int w = 0; w < 16; w++) t += hist[w * 257 + tid];
            s_merged[tid] = t;
        }
        __syncthreads();
        if (tid < 64) {   // single-wave suffix scan: 4 bins/lane + shfl_down
            unsigned u0 = s_merged[tid * 4 + 0], u1 = s_merged[tid * 4 + 1];
            unsigned u2 = s_merged[tid * 4 + 2], u3 = s_merged[tid * 4 + 3];
            unsigned sum4 = u0 + u1 + u2 + u3;
            unsigned x = sum4;
            #pragma unroll
            for (int off = 1; off < 64; off <<= 1) {
                unsigned y = __shfl_down(x, off, 64);
                if (tid + off < 64) x += y;
            }
            unsigned sf0 = x, sf1 = x - u0, sf2 = x - u0 - u1, sf3 = x - u0 - u1 - u2;
            unsigned sf4 = x - sum4;
            if (sf0 >= K && sf1 < K) { s_beta = tid * 4 + 0; s_K = K - sf1; }
            if (sf1 >= K && sf2 < K) { s_beta = tid * 4 + 1; s_K = K - sf2; }
            if (sf2 >= K && sf3 < K) { s_beta = tid * 4 + 2; s_K = K - sf3; }
            if (sf3 >= K && sf4 < K) { s_beta = tid * 4 + 3; s_K = K - sf4; }
        }
        __syncthreads();
        prefix |= (s_beta << shift);
        maskDone |= (0xFFu << shift);
        K = s_K;
        __syncthreads();
    }

    unsigned tBits = prefix;
    float t = __uint_as_float(tBits);

    unsigned mcnt = 0; float ssum = 0.f;
    for (int i = tid; i < P / 4; i += 1024) {
        float4 v = s_row4[i];
        float vv[4] = {v.x, v.y, v.z, v.w};
        #pragma unroll
        for (int e = 0; e < 4; e++)
            if (__float_as_uint(vv[e]) > tBits) { mcnt++; ssum += vv[e]; }
    }
    #pragma unroll
    for (int off = 32; off; off >>= 1) {
        mcnt += __shfl_xor(mcnt, off, 64);
        ssum += __shfl_xor(ssum, off, 64);
    }
    int lane = tid & 63;
    if (lane == 0) { sS[wid] = ssum; sM[wid] = mcnt; }
    __syncthreads();
    if (tid == 0) {
        float S = 0.f; unsigned M = 0;
        for (int w = 0; w < 16; w++) { S += sS[w]; M += sM[w]; }
        lc_b[b] += S + (float)(K0 - (int)M) * t;   // sole writer post-fix
    }
}

// ---------------- finalize ---------------------------------------------------
__global__ void k_final(const int* __restrict__ num_pos, const float* __restrict__ ll_b,
                        const float* __restrict__ lc_b, float* __restrict__ out) {
    int t = threadIdx.x;  // 64 threads
    int np = num_pos[t];
    float ll = ll_b[t];
    float lc = lc_b[t];
    #pragma unroll
    for (int off = 32; off; off >>= 1) {
        np += __shfl_xor(np, off, 64);
        ll += __shfl_xor(ll, off, 64);
        lc += __shfl_xor(lc, off, 64);
    }
    if (t == 0) {
        float tn = (float)np;
        out[0] = ll / tn;
        out[1] = lc / tn;
    }
}

extern "C" void kernel_launch(void* const* d_in, const int* in_sizes, int n_in,
                              void* d_out, int out_size, void* d_ws, size_t ws_size,
                              hipStream_t stream) {
    const float* arm_loc  = (const float*)d_in[0];
    const float* arm_conf = (const float*)d_in[1];
    const float* odm_loc  = (const float*)d_in[2];
    const float* odm_conf = (const float*)d_in[3];
    const float* priors   = (const float*)d_in[4];
    const float* truths   = (const float*)d_in[5];
    const int*   labels   = (const int*)d_in[6];
    float* out = (float*)d_out;

    char* ws = (char*)d_ws;
    const size_t BPTOT = (size_t)B * P;
    float* mine = (float*)ws;                                        // 4.18 MB
    unsigned long long* bp_part = (unsigned long long*)(ws + 4ull * BPTOT);  // 512 KB
    char* ws2 = ws + 4ull * BPTOT + 8ull * B * NCH * NOBJ;
    float* pll = (float*)ws2;                                        // B*NCH f32
    float* plc = (float*)(ws2 + 4ull * B * NCH);
    int*   pnp = (int*)(ws2 + 8ull * B * NCH);
    char* ws3 = ws2 + 12ull * B * NCH;
    float* ll_b = (float*)ws3;
    float* lc_b = (float*)(ws3 + 4 * B);
    int* num_pos = (int*)(ws3 + 8 * B);

    k_main<<<dim3(NCH, B), TPB, 0, stream>>>(arm_loc, arm_conf, odm_loc, odm_conf,
                                             priors, truths, labels,
                                             mine, bp_part, pll, plc, pnp);
    k_fix<<<B, 64, 0, stream>>>(arm_loc, arm_conf, odm_loc, odm_conf, priors,
                                truths, labels, bp_part, pll, plc, pnp,
                                mine, ll_b, lc_b, num_pos);
    k_select<<<B, 1024, 0, stream>>>(mine, num_pos, lc_b);
    k_final<<<1, 64, 0, stream>>>(num_pos, ll_b, lc_b, out);
}

// Round 8
// 237.514 us; speedup vs baseline: 2.5469x; 2.5469x over previous
//
#include <hip/hip_runtime.h>

#define B 64
#define P 16320
#define NOBJ 32
#define NC 21
#define TPB 256
#define NCH 64   // ceil(P/TPB); last chunk has 192 valid priors

__device__ constexpr float LN99 = 4.59511985013459f;  // softmax(c1)>0.01 <=> c0-c1 < ln99
#define SENT 0x407FFFFFFFFFFFFFULL                     // pack(-1.0f, prior 0)

struct Box { float x1, y1, x2, y2, area; };

__device__ __forceinline__ Box decode_box(float4 l, float4 pr) {
    Box b;
    float dcx = pr.x + l.x * 0.1f * pr.z;
    float dcy = pr.y + l.y * 0.1f * pr.w;
    float dw = pr.z * __expf(l.z * 0.2f);
    float dh = pr.w * __expf(l.w * 0.2f);
    b.x1 = dcx - dw * 0.5f; b.y1 = dcy - dh * 0.5f;
    b.x2 = dcx + dw * 0.5f; b.y2 = dcy + dh * 0.5f;
    b.area = (b.x2 - b.x1) * (b.y2 - b.y1);
    return b;
}
__device__ __forceinline__ float iou_box(const Box& bb, float4 t, float ta) {
    float iw = fmaxf(fminf(bb.x2, t.z) - fmaxf(bb.x1, t.x), 0.f);
    float ih = fmaxf(fminf(bb.y2, t.w) - fmaxf(bb.y1, t.y), 0.f);
    float inter = iw * ih;
    return inter * __builtin_amdgcn_rcpf(ta + bb.area - inter);
}
__device__ __forceinline__ float smoothl1(const Box& bb, float4 tb, float4 ol) {
    float rcx = (bb.x1 + bb.x2) * 0.5f, rcy = (bb.y1 + bb.y2) * 0.5f;
    float rw = bb.x2 - bb.x1, rh = bb.y2 - bb.y1;
    float g0 = ((tb.x + tb.z) * 0.5f - rcx) * __builtin_amdgcn_rcpf(0.1f * rw);
    float g1 = ((tb.y + tb.w) * 0.5f - rcy) * __builtin_amdgcn_rcpf(0.1f * rh);
    float g2 = __logf((tb.z - tb.x) * __builtin_amdgcn_rcpf(rw)) * 5.0f;
    float g3 = __logf((tb.w - tb.y) * __builtin_amdgcn_rcpf(rh)) * 5.0f;
    float gt[4] = {g0, g1, g2, g3};
    float od[4] = {ol.x, ol.y, ol.z, ol.w};
    float s = 0.f;
    #pragma unroll
    for (int k = 0; k < 4; k++) {
        float d = fabsf(od[k] - gt[k]);
        s += (d < 1.f) ? 0.5f * d * d : d - 0.5f;
    }
    return s;
}
__device__ __forceinline__ float lse_row(const float* row) {
    float m = row[0];
    #pragma unroll
    for (int k = 1; k < NC; k++) m = fmaxf(m, row[k]);
    float s = 0.f;
    #pragma unroll
    for (int k = 0; k < NC; k++) s += __expf(row[k] - m);
    return m + __logf(s);
}

// ---------------- k_main: decode + IoU + both argmaxes + CE + losses + mine --
// Grid (NCH, B). Per-truth winners via register pack -> 3-step pair shuffle ->
// shallow LDS tree (NO atomics, NO volatile). Per-block partial sums.
__global__ __launch_bounds__(TPB) void k_main(
    const float* __restrict__ arm_loc, const float* __restrict__ arm_conf,
    const float* __restrict__ odm_loc, const float* __restrict__ odm_conf,
    const float* __restrict__ priors, const float* __restrict__ truths,
    const int* __restrict__ labels,
    float* __restrict__ mine, unsigned long long* __restrict__ bp_part,
    float* __restrict__ pll, float* __restrict__ plc, int* __restrict__ pnp)
{
    int b = blockIdx.y, ch = blockIdx.x;
    int tid = threadIdx.x;
    int pbase = ch * TPB;
    int p = pbase + tid;
    bool active = p < P;

    __shared__ float soc[TPB * NC];                // 21504 B
    __shared__ float4 s_tr[NOBJ];
    __shared__ float s_ta[NOBJ];
    __shared__ int s_lab[NOBJ];
    __shared__ unsigned long long s1[NOBJ * 32];   // 8192 B
    __shared__ unsigned long long s2[NOBJ * 8];    // 2048 B
    __shared__ float sll[TPB / 64], slc[TPB / 64];
    __shared__ int snp[TPB / 64];

    if (tid < NOBJ) {
        float4 t = ((const float4*)truths)[b * NOBJ + tid];
        s_tr[tid] = t;
        s_ta[tid] = (t.z - t.x) * (t.w - t.y);
        s_lab[tid] = labels[b * NOBJ + tid];
    }
    {   // coalesced float4 staging of odm_conf (nval*NC divisible by 4)
        int nval = P - pbase; if (nval > TPB) nval = TPB;
        int tot4 = (nval * NC) >> 2;
        const float4* src = (const float4*)(odm_conf + ((size_t)b * P + pbase) * NC);
        float4* dst = (float4*)soc;
        for (int i = tid; i < tot4; i += TPB) dst[i] = src[i];
    }
    __syncthreads();

    Box bb = {0.f, 0.f, 0.f, 0.f, 0.f};
    bool resv = false;
    if (active) {
        size_t bpi = (size_t)b * P + p;
        float2 cc = ((const float2*)arm_conf)[bpi];
        resv = (cc.x - cc.y) < LN99;
        bb = decode_box(((const float4*)arm_loc)[bpi], ((const float4*)priors)[p]);
    }

    float bv = -1.f; int bj = 0;
    #pragma unroll
    for (int j = 0; j < NOBJ; j++) {
        float iou = iou_box(bb, s_tr[j], s_ta[j]);
        if (iou > bv) { bv = iou; bj = j; }           // first-max tie-break
        // per-truth key (reserve-masked): (iou|sign, ~p) -> ties pick min p
        unsigned long long k = 0ULL;
        if (resv)
            k = ((unsigned long long)(__float_as_uint(iou) | 0x80000000u) << 32)
              | (unsigned)~(unsigned)p;
        { unsigned long long o = __shfl_xor(k, 1, 64); if (o > k) k = o; }
        { unsigned long long o = __shfl_xor(k, 2, 64); if (o > k) k = o; }
        { unsigned long long o = __shfl_xor(k, 4, 64); if (o > k) k = o; }
        if ((tid & 7) == 0) s1[j * 32 + (tid >> 3)] = k;
    }

    int conf = -1;
    if (active) conf = resv ? ((bv >= 0.5f) ? s_lab[bj] + 1 : 0) : -1;

    float ll = 0.f, lc = 0.f; int np = 0;
    if (active) {
        size_t bpi = (size_t)b * P + p;
        const float* row = &soc[tid * NC];
        float lse = lse_row(row);
        int t0 = conf > 0 ? conf : 0;
        float ce = lse - row[t0];
        mine[bpi] = (conf == 0) ? ce : 0.f;
        if (conf > 0) {
            np = 1; lc = ce;
            float4 ol = ((const float4*)odm_loc)[bpi];
            ll = smoothl1(bb, s_tr[bj], ol);
        }
    }

    #pragma unroll
    for (int off = 32; off; off >>= 1) {
        ll += __shfl_xor(ll, off, 64);
        lc += __shfl_xor(lc, off, 64);
        np += __shfl_xor(np, off, 64);
    }
    int wid = tid >> 6, lane = tid & 63;
    if (lane == 0) { sll[wid] = ll; slc[wid] = lc; snp[wid] = np; }
    __syncthreads();                                   // s1 + sll visible

    {   // tree stage2: [32][32] -> [32][8]
        int j = tid >> 3, r = tid & 7;
        unsigned long long m = 0;
        #pragma unroll
        for (int i = 0; i < 4; i++) {
            unsigned long long v = s1[j * 32 + r * 4 + i];
            if (v > m) m = v;
        }
        s2[j * 8 + r] = m;
    }
    __syncthreads();
    if (tid < NOBJ) {                                  // [32][8] -> 1 per truth
        unsigned long long m = 0;
        #pragma unroll
        for (int i = 0; i < 8; i++) {
            unsigned long long v = s2[tid * 8 + i];
            if (v > m) m = v;
        }
        bp_part[((size_t)b * NCH + ch) * NOBJ + tid] = m;
    }
    if (tid == 0) {
        float a = 0.f, c = 0.f; int n = 0;
        #pragma unroll
        for (int w = 0; w < TPB / 64; w++) { a += sll[w]; c += slc[w]; n += snp[w]; }
        int idx = b * NCH + ch;
        pll[idx] = a; plc[idx] = c; pnp[idx] = n;
    }
}

// ---------------- k_fixsel: combine partials + force-match fix + top-K -------
// One 1024-thread block per batch. Stages mine into LDS once, patches the LDS
// copy for forced new-positives, then runs the radix select in-LDS.
__global__ __launch_bounds__(1024) void k_fixsel(
    const float* __restrict__ arm_loc, const float* __restrict__ arm_conf,
    const float* __restrict__ odm_loc, const float* __restrict__ odm_conf,
    const float* __restrict__ priors, const float* __restrict__ truths,
    const int* __restrict__ labels,
    const unsigned long long* __restrict__ bp_part,
    const float* __restrict__ pll, const float* __restrict__ plc,
    const int* __restrict__ pnp, const float* __restrict__ mine,
    float* __restrict__ ll_b, float* __restrict__ lc_b, int* __restrict__ num_pos)
{
    int b = blockIdx.x, tid = threadIdx.x;

    __shared__ float4 s_row4[P / 4];        // 65280 B
    __shared__ unsigned hist[16 * 257];     // per-wave + pad
    __shared__ unsigned s_merged[256];
    __shared__ unsigned s_beta, s_K;
    __shared__ float sS[16];
    __shared__ unsigned sM[16];
    __shared__ float4 s_tr[NOBJ];
    __shared__ float s_ta[NOBJ];
    __shared__ int s_lab[NOBJ];
    __shared__ unsigned s_p[NOBJ];
    __shared__ int s_K0;
    __shared__ float s_lc;

    const float4* src = (const float4*)(mine + (size_t)b * P);
    for (int i = tid; i < P / 4; i += 1024) s_row4[i] = src[i];

    if (tid < NOBJ) {
        float4 t = ((const float4*)truths)[b * NOBJ + tid];
        s_tr[tid] = t;
        s_ta[tid] = (t.z - t.x) * (t.w - t.y);
        s_lab[tid] = labels[b * NOBJ + tid];
        unsigned long long m = SENT;
        for (int c = 0; c < NCH; c++) {
            unsigned long long v = bp_part[((size_t)b * NCH + c) * NOBJ + tid];
            if (v > m) m = v;
        }
        s_p[tid] = ~(unsigned)(m & 0xFFFFFFFFULL);
    }
    __syncthreads();   // staging + s_p complete

    float ll = 0.f, lc = 0.f; int np = 0;
    if (tid < NCH) {   // NCH == 64: wave 0 holds the chunk partials
        int idx = b * NCH + tid;
        ll = pll[idx]; lc = plc[idx]; np = pnp[idx];
    }

    if (tid < NOBJ) {
        unsigned pstar = s_p[tid];
        bool alive = true;
        for (int j2 = tid + 1; j2 < NOBJ; j2++)
            if (s_p[j2] == pstar) alive = false;      // last j wins (JAX scatter)
        if (alive) {
            size_t bpi = (size_t)b * P + pstar;
            float2 cc = ((const float2*)arm_conf)[bpi];
            bool resv = (cc.x - cc.y) < LN99;
            if (resv) {   // non-reserve forced prior stays conf=-1 (ref order)
                Box bb = decode_box(((const float4*)arm_loc)[bpi],
                                    ((const float4*)priors)[pstar]);
                float bv = -1.f; int bj = 0;
                #pragma unroll
                for (int j = 0; j < NOBJ; j++) {
                    float iou = iou_box(bb, s_tr[j], s_ta[j]);
                    if (iou > bv) { bv = iou; bj = j; }
                }
                int old_conf = (bv >= 0.5f) ? s_lab[bj] + 1 : 0;
                const float* row = odm_conf + bpi * NC;
                float lse = lse_row(row);
                int new_conf = s_lab[tid] + 1;
                float ce_new = lse - row[new_conf];
                float4 ol = ((const float4*)odm_loc)[bpi];
                float sl_new = smoothl1(bb, s_tr[tid], ol);
                if (old_conf > 0) {
                    float ce_old = lse - row[old_conf];
                    float sl_old = smoothl1(bb, s_tr[bj], ol);
                    lc += ce_new - ce_old;
                    ll += sl_new - sl_old;
                } else {
                    lc += ce_new; ll += sl_new; np += 1;
                    ((float*)s_row4)[pstar] = 0.f;    // was a mining candidate
                }
            }
        }
    }

    if (tid < 64) {   // wave 0 reduce (fix deltas live in lanes 0..31)
        #pragma unroll
        for (int off = 32; off; off >>= 1) {
            ll += __shfl_xor(ll, off, 64);
            lc += __shfl_xor(lc, off, 64);
            np += __shfl_xor(np, off, 64);
        }
        if (tid == 0) {
            ll_b[b] = ll; num_pos[b] = np; s_lc = lc;
            int K0 = np * 3; if (K0 > P - 1) K0 = P - 1;
            s_K0 = K0;
        }
    }
    __syncthreads();   // patches + s_K0 visible

    int K0 = s_K0;
    if (K0 <= 0) { if (tid == 0) lc_b[b] = s_lc; return; }

    unsigned K = (unsigned)K0, prefix = 0, maskDone = 0;
    int wid = tid >> 6;

    for (int pass = 0; pass < 4; pass++) {
        int shift = 24 - pass * 8;
        for (int i = tid; i < 16 * 257; i += 1024) hist[i] = 0;
        __syncthreads();
        for (int i = tid; i < P / 4; i += 1024) {
            float4 v = s_row4[i];
            float vv[4] = {v.x, v.y, v.z, v.w};
            #pragma unroll
            for (int e = 0; e < 4; e++) {
                unsigned bits = __float_as_uint(vv[e]);
                if ((bits & maskDone) == prefix)
                    atomicAdd(&hist[wid * 257 + ((bits >> shift) & 255u)], 1u);
            }
        }
        __syncthreads();
        if (tid < 256) {
            unsigned t = 0;
            #pragma unroll
            for (int w = 0; w < 16; w++) t += hist[w * 257 + tid];
            s_merged[tid] = t;
        }
        __syncthreads();
        if (tid < 64) {   // single-wave suffix scan: 4 bins/lane + shfl_down
            unsigned u0 = s_merged[tid * 4 + 0], u1 = s_merged[tid * 4 + 1];
            unsigned u2 = s_merged[tid * 4 + 2], u3 = s_merged[tid * 4 + 3];
            unsigned sum4 = u0 + u1 + u2 + u3;
            unsigned x = sum4;
            #pragma unroll
            for (int off = 1; off < 64; off <<= 1) {
                unsigned y = __shfl_down(x, off, 64);
                if (tid + off < 64) x += y;
            }
            unsigned sf0 = x, sf1 = x - u0, sf2 = x - u0 - u1, sf3 = x - u0 - u1 - u2;
            unsigned sf4 = x - sum4;
            if (sf0 >= K && sf1 < K) { s_beta = tid * 4 + 0; s_K = K - sf1; }
            if (sf1 >= K && sf2 < K) { s_beta = tid * 4 + 1; s_K = K - sf2; }
            if (sf2 >= K && sf3 < K) { s_beta = tid * 4 + 2; s_K = K - sf3; }
            if (sf3 >= K && sf4 < K) { s_beta = tid * 4 + 3; s_K = K - sf4; }
        }
        __syncthreads();
        prefix |= (s_beta << shift);
        maskDone |= (0xFFu << shift);
        K = s_K;
        __syncthreads();
    }

    unsigned tBits = prefix;
    float t = __uint_as_float(tBits);

    unsigned mcnt = 0; float ssum = 0.f;
    for (int i = tid; i < P / 4; i += 1024) {
        float4 v = s_row4[i];
        float vv[4] = {v.x, v.y, v.z, v.w};
        #pragma unroll
        for (int e = 0; e < 4; e++)
            if (__float_as_uint(vv[e]) > tBits) { mcnt++; ssum += vv[e]; }
    }
    #pragma unroll
    for (int off = 32; off; off >>= 1) {
        mcnt += __shfl_xor(mcnt, off, 64);
        ssum += __shfl_xor(ssum, off, 64);
    }
    int lane = tid & 63;
    if (lane == 0) { sS[wid] = ssum; sM[wid] = mcnt; }
    __syncthreads();
    if (tid == 0) {
        float S = 0.f; unsigned M = 0;
        for (int w = 0; w < 16; w++) { S += sS[w]; M += sM[w]; }
        lc_b[b] = s_lc + S + (float)(K0 - (int)M) * t;
    }
}

// ---------------- finalize ---------------------------------------------------
__global__ void k_final(const int* __restrict__ num_pos, const float* __restrict__ ll_b,
                        const float* __restrict__ lc_b, float* __restrict__ out) {
    int t = threadIdx.x;  // 64 threads
    int np = num_pos[t];
    float ll = ll_b[t];
    float lc = lc_b[t];
    #pragma unroll
    for (int off = 32; off; off >>= 1) {
        np += __shfl_xor(np, off, 64);
        ll += __shfl_xor(ll, off, 64);
        lc += __shfl_xor(lc, off, 64);
    }
    if (t == 0) {
        float tn = (float)np;
        out[0] = ll / tn;
        out[1] = lc / tn;
    }
}

extern "C" void kernel_launch(void* const* d_in, const int* in_sizes, int n_in,
                              void* d_out, int out_size, void* d_ws, size_t ws_size,
                              hipStream_t stream) {
    const float* arm_loc  = (const float*)d_in[0];
    const float* arm_conf = (const float*)d_in[1];
    const float* odm_loc  = (const float*)d_in[2];
    const float* odm_conf = (const float*)d_in[3];
    const float* priors   = (const float*)d_in[4];
    const float* truths   = (const float*)d_in[5];
    const int*   labels   = (const int*)d_in[6];
    float* out = (float*)d_out;

    char* ws = (char*)d_ws;
    const size_t BPTOT = (size_t)B * P;
    float* mine = (float*)ws;                                        // 4.18 MB
    unsigned long long* bp_part = (unsigned long long*)(ws + 4ull * BPTOT);  // 1 MB
    char* ws2 = ws + 4ull * BPTOT + 8ull * B * NCH * NOBJ;
    float* pll = (float*)ws2;                                        // B*NCH f32
    float* plc = (float*)(ws2 + 4ull * B * NCH);
    int*   pnp = (int*)(ws2 + 8ull * B * NCH);
    char* ws3 = ws2 + 12ull * B * NCH;
    float* ll_b = (float*)ws3;
    float* lc_b = (float*)(ws3 + 4 * B);
    int* num_pos = (int*)(ws3 + 8 * B);

    k_main<<<dim3(NCH, B), TPB, 0, stream>>>(arm_loc, arm_conf, odm_loc, odm_conf,
                                             priors, truths, labels,
                                             mine, bp_part, pll, plc, pnp);
    k_fixsel<<<B, 1024, 0, stream>>>(arm_loc, arm_conf, odm_loc, odm_conf, priors,
                                     truths, labels, bp_part, pll, plc, pnp,
                                     mine, ll_b, lc_b, num_pos);
    k_final<<<1, 64, 0, stream>>>(num_pos, ll_b, lc_b, out);
}